// Round 1
// baseline (1401.905 us; speedup 1.0000x reference)
//
#include <hip/hip_runtime.h>
#include <hip/hip_bf16.h>

#define Bb 128
#define Nn 256
#define Kk 4
#define Ee 300
#define Hh 150
#define H3 450
#define Vv 32000
#define NROW 384        // 3 trees * B
#define HP 152          // padded H (16B-aligned rows)
#define PROJC 600       // 450 iou + 150 f

typedef __hip_bfloat16 bf16;

__device__ __forceinline__ float sigmoidf_(float x) { return 1.0f / (1.0f + __expf(-x)); }
__device__ __forceinline__ float tanh_fast(float x) { return 1.0f - 2.0f / (__expf(2.0f * x) + 1.0f); }

// ---------------- vocab projection: proj[v][0:450] = emb[v]@W_iou + b_iou,
//                  proj[v][450:600] = emb[v]@W_f + b_f  (bf16 out) ----------
__global__ __launch_bounds__(256) void k_vocab_proj(
    const float* __restrict__ emb, const float* __restrict__ W_iou,
    const float* __restrict__ b_iou, const float* __restrict__ W_f,
    const float* __restrict__ b_f, bf16* __restrict__ proj)
{
    __shared__ __align__(16) float xs[32][Ee];
    const int tid = threadIdx.x;
    const int v0 = blockIdx.x * 32;

    const float4* emb4 = (const float4*)emb;   // 300 floats = 75 float4 per row
    for (int i = tid; i < 32 * 75; i += 256) {
        int r = i / 75, q = i % 75;
        ((float4*)xs[r])[q] = emb4[(long)(v0 + r) * 75 + q];
    }
    __syncthreads();

    int   col[3];  bool valid[3];  float bias[3];
    #pragma unroll
    for (int i = 0; i < 3; i++) {
        col[i] = tid + 256 * i;
        valid[i] = col[i] < PROJC;
        bias[i] = valid[i] ? (col[i] < H3 ? b_iou[col[i]] : b_f[col[i] - H3]) : 0.0f;
    }

    float acc[32][3];
    #pragma unroll
    for (int r = 0; r < 32; r++)
        #pragma unroll
        for (int i = 0; i < 3; i++) acc[r][i] = bias[i];

    for (int e = 0; e < Ee; e += 4) {
        float w[3][4];
        #pragma unroll
        for (int i = 0; i < 3; i++)
            #pragma unroll
            for (int d = 0; d < 4; d++)
                w[i][d] = valid[i] ? (col[i] < H3 ? W_iou[(e + d) * H3 + col[i]]
                                                  : W_f[(e + d) * Hh + (col[i] - H3)])
                                   : 0.0f;
        #pragma unroll
        for (int r = 0; r < 32; r++) {
            float4 x = *(const float4*)&xs[r][e];
            #pragma unroll
            for (int i = 0; i < 3; i++) {
                acc[r][i] = fmaf(x.x, w[i][0], acc[r][i]);
                acc[r][i] = fmaf(x.y, w[i][1], acc[r][i]);
                acc[r][i] = fmaf(x.z, w[i][2], acc[r][i]);
                acc[r][i] = fmaf(x.w, w[i][3], acc[r][i]);
            }
        }
    }

    #pragma unroll
    for (int i = 0; i < 3; i++) {
        if (!valid[i]) continue;
        #pragma unroll
        for (int r = 0; r < 32; r++)
            proj[(long)(v0 + r) * PROJC + col[i]] = __float2bfloat16(acc[r][i]);
    }
}

// ---------------- leaves: nodes t in [64,256): no children ----------------
__global__ __launch_bounds__(256) void k_leaf(
    const int* __restrict__ tq, const int* __restrict__ tp, const int* __restrict__ tn,
    const bf16* __restrict__ proj, float* __restrict__ h, float* __restrict__ c)
{
    long i = (long)blockIdx.x * 256 + threadIdx.x;
    const long total = (long)NROW * 192 * HP;
    if (i >= total) return;
    int k = (int)(i % HP);
    long rt = i / HP;
    int t = 64 + (int)(rt % 192);
    int r = (int)(rt / 192);              // row = g*128 + b
    long hidx = ((long)r * Nn + t) * HP + k;
    if (k >= Hh) { h[hidx] = 0.0f; c[hidx] = 0.0f; return; }
    int g = r >> 7, b = r & 127;
    const int* tok = (g == 0) ? tq : (g == 1 ? tp : tn);
    int v = tok[b * Nn + t];
    const bf16* pr = proj + (long)v * PROJC;
    float iv = sigmoidf_(__bfloat162float(pr[k]));
    float ov = sigmoidf_(__bfloat162float(pr[Hh + k]));
    float uv = tanh_fast(__bfloat162float(pr[2 * Hh + k]));
    float cv = iv * uv;
    c[hidx] = cv;
    h[hidx] = ov * tanh_fast(cv);
}

// ---------------- internal nodes: one block = (node t, 16 rows) -----------
#define RT 16
__global__ __launch_bounds__(256) void k_internal(
    int t0,
    const int* __restrict__ tq, const int* __restrict__ tp, const int* __restrict__ tn,
    const int* __restrict__ children, const bf16* __restrict__ proj,
    const float* __restrict__ U_iou, const float* __restrict__ U_f,
    float* __restrict__ h, float* __restrict__ c)
{
    __shared__ __align__(16) float hk_s[RT][Kk][HP];     // later aliased as f_s
    __shared__ __align__(16) float hsum_s[RT][HP];
    __shared__ __align__(16) float iou_s[RT][H3];
    __shared__ int tok_s[RT];
    __shared__ int ch_s[Kk];

    const int tid = threadIdx.x;
    const int RB = NROW / RT;                 // 24 row-blocks per node
    const int t = t0 + blockIdx.x / RB;
    const int r0 = (blockIdx.x % RB) * RT;

    if (tid < Kk) ch_s[tid] = children[t * Kk + tid];
    if (tid < RT) {
        int rg = r0 + tid, g = rg >> 7, b = rg & 127;
        const int* tok = (g == 0) ? tq : (g == 1 ? tp : tn);
        tok_s[tid] = tok[b * Nn + t];
    }
    __syncthreads();
    int ch[Kk];
    #pragma unroll
    for (int j = 0; j < Kk; j++) ch[j] = ch_s[j];

    // stage children h rows (float4, zero if masked)
    const float4* h4 = (const float4*)h;
    for (int i = tid; i < RT * Kk * 38; i += 256) {
        int r = i / (Kk * 38), rem = i % (Kk * 38), j = rem / 38, q = rem % 38;
        float4 vv = make_float4(0.f, 0.f, 0.f, 0.f);
        if (ch[j] >= 0)
            vv = h4[(((long)(r0 + r) * Nn + ch[j]) * HP) / 4 + q];
        ((float4*)hk_s[r][j])[q] = vv;
    }
    __syncthreads();
    for (int i = tid; i < RT * HP; i += 256) {
        int r = i / HP, k = i % HP;
        hsum_s[r][k] = hk_s[r][0][k] + hk_s[r][1][k] + hk_s[r][2][k] + hk_s[r][3][k];
    }
    __syncthreads();

    // batched matvec: 1050 cols (450 iou + 4*150 f) over k=0..149
    float acc[RT][5];
    #pragma unroll
    for (int r = 0; r < RT; r++)
        #pragma unroll
        for (int i = 0; i < 5; i++) acc[r][i] = 0.0f;

    bool valid[5]; const float* ub[5]; int ustr[5]; const float* lb[5]; int lstr[5];
    #pragma unroll
    for (int i = 0; i < 5; i++) {
        int cg = tid + 256 * i;
        valid[i] = cg < (H3 + Kk * Hh);
        int cgs = valid[i] ? cg : 0;
        if (cgs < H3) {
            ub[i] = U_iou + cgs;  ustr[i] = H3;
            lb[i] = &hsum_s[0][0]; lstr[i] = HP;
        } else {
            int f = cgs - H3, j = f / Hh, fc = f % Hh;
            ub[i] = U_f + fc;  ustr[i] = Hh;
            lb[i] = &hk_s[0][j][0]; lstr[i] = Kk * HP;
        }
    }

    for (int k = 0; k < 148; k += 4) {
        float w[5][4];
        #pragma unroll
        for (int i = 0; i < 5; i++)
            #pragma unroll
            for (int d = 0; d < 4; d++)
                w[i][d] = valid[i] ? ub[i][(k + d) * ustr[i]] : 0.0f;
        #pragma unroll
        for (int r = 0; r < RT; r++) {
            #pragma unroll
            for (int i = 0; i < 5; i++) {
                float4 x = *(const float4*)(lb[i] + r * lstr[i] + k);
                acc[r][i] = fmaf(x.x, w[i][0], acc[r][i]);
                acc[r][i] = fmaf(x.y, w[i][1], acc[r][i]);
                acc[r][i] = fmaf(x.z, w[i][2], acc[r][i]);
                acc[r][i] = fmaf(x.w, w[i][3], acc[r][i]);
            }
        }
    }
    #pragma unroll
    for (int kk = 148; kk < 150; kk++) {
        float w[5];
        #pragma unroll
        for (int i = 0; i < 5; i++) w[i] = valid[i] ? ub[i][kk * ustr[i]] : 0.0f;
        #pragma unroll
        for (int r = 0; r < RT; r++)
            #pragma unroll
            for (int i = 0; i < 5; i++)
                acc[r][i] = fmaf(lb[i][r * lstr[i] + kk], w[i], acc[r][i]);
    }

    __syncthreads();   // matvec reads of hk_s done; safe to alias
    float (*f_s)[Kk][HP] = hk_s;
    #pragma unroll
    for (int i = 0; i < 5; i++) {
        if (!valid[i]) continue;
        int cg = tid + 256 * i;
        #pragma unroll
        for (int r = 0; r < RT; r++) {
            if (cg < H3) iou_s[r][cg] = acc[r][i];
            else { int f = cg - H3; f_s[r][f / Hh][f % Hh] = acc[r][i]; }
        }
    }
    __syncthreads();

    // fuse gates, read children c, write h/c
    for (int i2 = tid; i2 < RT * HP; i2 += 256) {
        int r = i2 / HP, k = i2 % HP;
        int rg = r0 + r;
        long hidx = ((long)rg * Nn + t) * HP + k;
        if (k >= Hh) { h[hidx] = 0.0f; c[hidx] = 0.0f; continue; }
        int v = tok_s[r];
        const bf16* pr = proj + (long)v * PROJC;
        float iv = sigmoidf_(__bfloat162float(pr[k])          + iou_s[r][k]);
        float ov = sigmoidf_(__bfloat162float(pr[Hh + k])     + iou_s[r][Hh + k]);
        float uv = tanh_fast(__bfloat162float(pr[2 * Hh + k]) + iou_s[r][2 * Hh + k]);
        float fpre = __bfloat162float(pr[3 * Hh + k]);
        float cv = iv * uv;
        #pragma unroll
        for (int j = 0; j < Kk; j++) {
            if (ch[j] >= 0) {
                float fv = sigmoidf_(fpre + f_s[r][j][k]);
                float ck = c[((long)rg * Nn + ch[j]) * HP + k];
                cv = fmaf(fv, ck, cv);
            }
        }
        c[hidx] = cv;
        h[hidx] = ov * tanh_fast(cv);
    }
}

// ---------------- cosine + triplet loss ----------------
__global__ __launch_bounds__(64) void k_cos(const float* __restrict__ c, float* __restrict__ out)
{
    int b = blockIdx.x, tid = threadIdx.x;
    const float* qc = c + ((long)(0 * Bb + b) * Nn + 0) * HP;
    const float* pc = c + ((long)(1 * Bb + b) * Nn + 0) * HP;
    const float* nc = c + ((long)(2 * Bb + b) * Nn + 0) * HP;
    float qp = 0, qn = 0, qq = 0, pp = 0, nn2 = 0;
    for (int k = tid; k < Hh; k += 64) {
        float qv = qc[k], pv = pc[k], nv = nc[k];
        qp += qv * pv; qn += qv * nv; qq += qv * qv; pp += pv * pv; nn2 += nv * nv;
    }
    #pragma unroll
    for (int off = 32; off > 0; off >>= 1) {
        qp += __shfl_down(qp, off, 64);
        qn += __shfl_down(qn, off, 64);
        qq += __shfl_down(qq, off, 64);
        pp += __shfl_down(pp, off, 64);
        nn2 += __shfl_down(nn2, off, 64);
    }
    if (tid == 0) {
        float a = qp / (sqrtf(qq * pp) + 1e-8f);
        float d = qn / (sqrtf(qq * nn2) + 1e-8f);
        out[b] = fmaxf(0.0f, 1.0f - a + d);
    }
}

extern "C" void kernel_launch(void* const* d_in, const int* in_sizes, int n_in,
                              void* d_out, int out_size, void* d_ws, size_t ws_size,
                              hipStream_t stream)
{
    const int*   tq       = (const int*)d_in[0];
    const int*   tp       = (const int*)d_in[1];
    const int*   tn       = (const int*)d_in[2];
    const int*   children = (const int*)d_in[3];
    const float* emb      = (const float*)d_in[4];
    const float* W_iou    = (const float*)d_in[5];
    const float* U_iou    = (const float*)d_in[6];
    const float* b_iou    = (const float*)d_in[7];
    const float* W_f      = (const float*)d_in[8];
    const float* U_f      = (const float*)d_in[9];
    const float* b_f      = (const float*)d_in[10];
    float* out = (float*)d_out;

    char* ws = (char*)d_ws;
    bf16*  proj = (bf16*)ws;                                   // 32000*600*2 = 38,400,000 B
    float* h    = (float*)(ws + 38400000);                     // 384*256*152*4 = 59,768,832 B
    float* c    = (float*)(ws + 38400000 + 59768832);

    k_vocab_proj<<<Vv / 32, 256, 0, stream>>>(emb, W_iou, b_iou, W_f, b_f, proj);
    k_leaf<<<(int)(((long)NROW * 192 * HP + 255) / 256), 256, 0, stream>>>(tq, tp, tn, proj, h, c);
    k_internal<<<43 * 24, 256, 0, stream>>>(21, tq, tp, tn, children, proj, U_iou, U_f, h, c);
    k_internal<<<16 * 24, 256, 0, stream>>>(5,  tq, tp, tn, children, proj, U_iou, U_f, h, c);
    k_internal<<<4 * 24, 256, 0, stream>>>(1,   tq, tp, tn, children, proj, U_iou, U_f, h, c);
    k_internal<<<1 * 24, 256, 0, stream>>>(0,   tq, tp, tn, children, proj, U_iou, U_f, h, c);
    k_cos<<<Bb, 64, 0, stream>>>(c, out);
}

// Round 2
// 414.326 us; speedup vs baseline: 3.3836x; 3.3836x over previous
//
#include <hip/hip_runtime.h>
#include <hip/hip_bf16.h>

typedef short short8 __attribute__((ext_vector_type(8)));
typedef float floatx4 __attribute__((ext_vector_type(4)));
typedef unsigned short ushort;

#define Bb 128
#define Nn 256
#define Hh 150
#define HK 160        // padded K / col dim for h,c storage
#define Vv 32000
#define NROW 384      // 3 trees * B
#define PROJC 600

__device__ __forceinline__ float sigf(float x) { return 1.0f / (1.0f + __expf(-x)); }
__device__ __forceinline__ float tanhf_(float x) { return 1.0f - 2.0f / (__expf(2.0f * x) + 1.0f); }
__device__ __forceinline__ float bf2f(ushort s) { union { float f; unsigned u; } v; v.u = ((unsigned)s) << 16; return v.f; }
__device__ __forceinline__ ushort f2bf(float f) { __hip_bfloat16 h = __float2bfloat16(f); return *(ushort*)&h; }

// ---------------- prep: transpose weights to bf16 B-operand layout ----------
// Wt[608][320]  (vocab proj B: cols 0..449 = W_iou, 450..599 = W_f)
// Uti[464][160] (U_iou^T), Utf[160][160] (U_f^T), biasw[608]
__global__ __launch_bounds__(256) void k_prep(
    const float* __restrict__ W_iou, const float* __restrict__ W_f,
    const float* __restrict__ U_iou, const float* __restrict__ U_f,
    const float* __restrict__ b_iou, const float* __restrict__ b_f,
    short* __restrict__ Wt, short* __restrict__ Uti, short* __restrict__ Utf,
    float* __restrict__ biasw)
{
    int idx = blockIdx.x * 256 + threadIdx.x;
    const int nWt = 608 * 320, nUi = 464 * 160, nUf = 160 * 160;
    if (idx < nWt) {
        int n = idx / 320, k = idx % 320;
        float v = 0.f;
        if (k < 300) { if (n < 450) v = W_iou[k * 450 + n]; else if (n < 600) v = W_f[k * 150 + (n - 450)]; }
        Wt[idx] = (short)f2bf(v);
    } else if (idx < nWt + nUi) {
        int i2 = idx - nWt; int n = i2 / 160, k = i2 % 160;
        float v = (k < 150 && n < 450) ? U_iou[k * 450 + n] : 0.f;
        Uti[i2] = (short)f2bf(v);
    } else if (idx < nWt + nUi + nUf) {
        int i2 = idx - nWt - nUi; int n = i2 / 160, k = i2 % 160;
        float v = (k < 150) ? U_f[k * 150 + n] : 0.f;
        Utf[i2] = (short)f2bf(v);
    } else if (idx < nWt + nUi + nUf + 608) {
        int n = idx - nWt - nUi - nUf;
        biasw[n] = n < 450 ? b_iou[n] : (n < 600 ? b_f[n - 450] : 0.f);
    }
}

// ---------------- vocab projection via MFMA: proj[32000][600] bf16 ----------
__global__ __launch_bounds__(256) void k_vproj(
    const float* __restrict__ emb, const short* __restrict__ Wt,
    const float* __restrict__ biasw, ushort* __restrict__ proj)
{
    __shared__ __align__(16) short As[64 * 328];   // 64 rows x 320 k (stride 328: 2-way-free banks)
    const int tid = threadIdx.x;
    const int v0 = blockIdx.x * 64;

    for (int i = tid; i < 64 * 80; i += 256) {
        int r = i / 80, q = i % 80, k0 = q * 4;
        short4 sv;
        if (k0 < 300) {
            float4 x = *(const float4*)(emb + (long)(v0 + r) * 300 + k0);
            sv.x = (short)f2bf(x.x); sv.y = (short)f2bf(x.y);
            sv.z = (short)f2bf(x.z); sv.w = (short)f2bf(x.w);
        } else sv = make_short4(0, 0, 0, 0);
        *(short4*)&As[r * 328 + k0] = sv;
    }
    __syncthreads();

    const int w = tid >> 6, lane = tid & 63;
    const int m = lane & 15, kq = (lane >> 4) * 8;
    const short* arow = &As[(w * 16 + m) * 328 + kq];

    for (int nt = 0; nt < 38; nt++) {
        int col = nt * 16 + m;
        const short* bp = Wt + (long)col * 320 + kq;
        floatx4 acc = {0.f, 0.f, 0.f, 0.f};
        #pragma unroll
        for (int ks = 0; ks < 10; ks++) {
            short8 a = *(const short8*)(arow + ks * 32);
            short8 b = *(const short8*)(bp + ks * 32);
            acc = __builtin_amdgcn_mfma_f32_16x16x32_bf16(a, b, acc, 0, 0, 0);
        }
        if (col < PROJC) {
            float bias = biasw[col];
            int rbase = v0 + w * 16 + (lane >> 4) * 4;
            #pragma unroll
            for (int reg = 0; reg < 4; reg++)
                proj[(long)(rbase + reg) * PROJC + col] = f2bf(acc[reg] + bias);
        }
    }
}

// ---------------- leaves: nodes t in [64,256) ----------------
__global__ __launch_bounds__(256) void k_leaf(
    const int* __restrict__ tq, const int* __restrict__ tp, const int* __restrict__ tn,
    const ushort* __restrict__ proj, ushort* __restrict__ h, float* __restrict__ c)
{
    long i = (long)blockIdx.x * 256 + threadIdx.x;   // < 384*192*160 exactly
    int k = (int)(i % HK);
    long rt = i / HK;
    int t = 64 + (int)(rt % 192);
    int rg = (int)(rt / 192);
    long o = ((long)rg * Nn + t) * HK + k;
    if (k >= Hh) { h[o] = 0; c[o] = 0.f; return; }
    int g = rg >> 7, b = rg & 127;
    const int* tok = (g == 0) ? tq : (g == 1 ? tp : tn);
    int v = tok[b * Nn + t];
    const ushort* pr = proj + (long)v * PROJC;
    float iv = sigf(bf2f(pr[k]));
    float ov = sigf(bf2f(pr[150 + k]));
    float uv = tanhf_(bf2f(pr[300 + k]));
    float cv = iv * uv;
    c[o] = cv;
    h[o] = f2bf(ov * tanhf_(cv));
}

// ---------------- internal level: fused MFMA + gates ----------------
// block = (node, 16 rows); 4 waves split the 10 column-tiles; all 7 gate
// segments for one column-tile live in one wave's registers -> no preact LDS.
__global__ __launch_bounds__(256) void k_level(
    int t0,
    const int* __restrict__ tq, const int* __restrict__ tp, const int* __restrict__ tn,
    const int* __restrict__ children, const ushort* __restrict__ proj,
    const short* __restrict__ Uti, const short* __restrict__ Utf,
    ushort* __restrict__ h, float* __restrict__ c)
{
    __shared__ __align__(16) short As[5][16][168];  // seg0=sum, 1..4=children; stride 168: 2-way-free
    __shared__ int ch_s[4];
    __shared__ int tok_s[16];

    const int tid = threadIdx.x;
    const int t = t0 + blockIdx.x / 24;
    const int r0 = (blockIdx.x % 24) * 16;

    if (tid < 4) ch_s[tid] = children[t * 4 + tid];
    if (tid < 16) {
        int rg = r0 + tid, g = rg >> 7, b = rg & 127;
        const int* tok = (g == 0) ? tq : (g == 1 ? tp : tn);
        tok_s[tid] = tok[b * Nn + t];
    }
    __syncthreads();
    const int ch0 = ch_s[0], ch1 = ch_s[1], ch2 = ch_s[2], ch3 = ch_s[3];

    // stage child h rows (bf16) + compute bf16 row-sum
    for (int i = tid; i < 16 * 20; i += 256) {
        int r = i / 20, k0 = (i % 20) * 8;
        long rowb = (long)(r0 + r) * Nn;
        int4 z = make_int4(0, 0, 0, 0);
        int4 v0 = ch0 >= 0 ? *(const int4*)(h + (rowb + ch0) * HK + k0) : z;
        int4 v1 = ch1 >= 0 ? *(const int4*)(h + (rowb + ch1) * HK + k0) : z;
        int4 v2 = ch2 >= 0 ? *(const int4*)(h + (rowb + ch2) * HK + k0) : z;
        int4 v3 = ch3 >= 0 ? *(const int4*)(h + (rowb + ch3) * HK + k0) : z;
        *(int4*)&As[1][r][k0] = v0;
        *(int4*)&As[2][r][k0] = v1;
        *(int4*)&As[3][r][k0] = v2;
        *(int4*)&As[4][r][k0] = v3;
        ushort s[8];
        const ushort* p0 = (const ushort*)&v0; const ushort* p1 = (const ushort*)&v1;
        const ushort* p2 = (const ushort*)&v2; const ushort* p3 = (const ushort*)&v3;
        #pragma unroll
        for (int e = 0; e < 8; e++)
            s[e] = f2bf(bf2f(p0[e]) + bf2f(p1[e]) + bf2f(p2[e]) + bf2f(p3[e]));
        *(int4*)&As[0][r][k0] = *(int4*)s;
    }
    __syncthreads();

    const int w = tid >> 6, lane = tid & 63;
    const int m = lane & 15, kq = (lane >> 4) * 8;

    for (int nt = w; nt < 10; nt += 4) {
        int col = nt * 16 + m;
        const short* bi = Uti + (long)(col) * HK + kq;
        const short* bo = Uti + (long)(150 + col) * HK + kq;
        const short* bu = Uti + (long)(300 + col) * HK + kq;
        const short* bff = Utf + (long)col * HK + kq;
        floatx4 ai = {0.f,0.f,0.f,0.f}, ao = ai, au = ai;
        floatx4 af0 = ai, af1 = ai, af2 = ai, af3 = ai;
        #pragma unroll
        for (int ks = 0; ks < 5; ks++) {
            short8 asum = *(const short8*)&As[0][m][kq + ks * 32];
            short8 ac0  = *(const short8*)&As[1][m][kq + ks * 32];
            short8 ac1  = *(const short8*)&As[2][m][kq + ks * 32];
            short8 ac2  = *(const short8*)&As[3][m][kq + ks * 32];
            short8 ac3  = *(const short8*)&As[4][m][kq + ks * 32];
            short8 vbi = *(const short8*)(bi + ks * 32);
            short8 vbo = *(const short8*)(bo + ks * 32);
            short8 vbu = *(const short8*)(bu + ks * 32);
            short8 vbf = *(const short8*)(bff + ks * 32);
            ai  = __builtin_amdgcn_mfma_f32_16x16x32_bf16(asum, vbi, ai, 0, 0, 0);
            ao  = __builtin_amdgcn_mfma_f32_16x16x32_bf16(asum, vbo, ao, 0, 0, 0);
            au  = __builtin_amdgcn_mfma_f32_16x16x32_bf16(asum, vbu, au, 0, 0, 0);
            af0 = __builtin_amdgcn_mfma_f32_16x16x32_bf16(ac0,  vbf, af0, 0, 0, 0);
            af1 = __builtin_amdgcn_mfma_f32_16x16x32_bf16(ac1,  vbf, af1, 0, 0, 0);
            af2 = __builtin_amdgcn_mfma_f32_16x16x32_bf16(ac2,  vbf, af2, 0, 0, 0);
            af3 = __builtin_amdgcn_mfma_f32_16x16x32_bf16(ac3,  vbf, af3, 0, 0, 0);
        }

        int rbase = (lane >> 4) * 4;
        if (col < Hh) {
            #pragma unroll
            for (int reg = 0; reg < 4; reg++) {
                int r = rbase + reg, rg = r0 + r;
                int v = tok_s[r];
                const ushort* pr = proj + (long)v * PROJC;
                float iv = sigf(bf2f(pr[col])       + ai[reg]);
                float ov = sigf(bf2f(pr[150 + col]) + ao[reg]);
                float uv = tanhf_(bf2f(pr[300 + col]) + au[reg]);
                float fpre = bf2f(pr[450 + col]);
                float cv = iv * uv;
                long crow = (long)rg * Nn;
                if (ch0 >= 0) cv = fmaf(sigf(fpre + af0[reg]), c[(crow + ch0) * HK + col], cv);
                if (ch1 >= 0) cv = fmaf(sigf(fpre + af1[reg]), c[(crow + ch1) * HK + col], cv);
                if (ch2 >= 0) cv = fmaf(sigf(fpre + af2[reg]), c[(crow + ch2) * HK + col], cv);
                if (ch3 >= 0) cv = fmaf(sigf(fpre + af3[reg]), c[(crow + ch3) * HK + col], cv);
                long o = (crow + t) * HK + col;
                c[o] = cv;
                h[o] = f2bf(ov * tanhf_(cv));
            }
        } else {
            #pragma unroll
            for (int reg = 0; reg < 4; reg++) {
                long o = ((long)(r0 + rbase + reg) * Nn + t) * HK + col;
                c[o] = 0.f; h[o] = 0;
            }
        }
    }
}

// ---------------- cosine + triplet loss ----------------
__global__ __launch_bounds__(64) void k_cos(const float* __restrict__ c, float* __restrict__ out)
{
    int b = blockIdx.x, tid = threadIdx.x;
    const float* qc = c + (long)(0 * Bb + b) * Nn * HK;
    const float* pc = c + (long)(1 * Bb + b) * Nn * HK;
    const float* nc = c + (long)(2 * Bb + b) * Nn * HK;
    float qp = 0, qn = 0, qq = 0, pp = 0, nn2 = 0;
    for (int k = tid; k < Hh; k += 64) {
        float qv = qc[k], pv = pc[k], nv = nc[k];
        qp += qv * pv; qn += qv * nv; qq += qv * qv; pp += pv * pv; nn2 += nv * nv;
    }
    #pragma unroll
    for (int off = 32; off > 0; off >>= 1) {
        qp += __shfl_down(qp, off, 64);
        qn += __shfl_down(qn, off, 64);
        qq += __shfl_down(qq, off, 64);
        pp += __shfl_down(pp, off, 64);
        nn2 += __shfl_down(nn2, off, 64);
    }
    if (tid == 0) {
        float a = qp / (sqrtf(qq * pp) + 1e-8f);
        float d = qn / (sqrtf(qq * nn2) + 1e-8f);
        out[b] = fmaxf(0.0f, 1.0f - a + d);
    }
}

extern "C" void kernel_launch(void* const* d_in, const int* in_sizes, int n_in,
                              void* d_out, int out_size, void* d_ws, size_t ws_size,
                              hipStream_t stream)
{
    const int*   tq       = (const int*)d_in[0];
    const int*   tp       = (const int*)d_in[1];
    const int*   tn       = (const int*)d_in[2];
    const int*   children = (const int*)d_in[3];
    const float* emb      = (const float*)d_in[4];
    const float* W_iou    = (const float*)d_in[5];
    const float* U_iou    = (const float*)d_in[6];
    const float* b_iou    = (const float*)d_in[7];
    const float* W_f      = (const float*)d_in[8];
    const float* U_f      = (const float*)d_in[9];
    const float* b_f      = (const float*)d_in[10];
    float* out = (float*)d_out;

    char* ws = (char*)d_ws;
    ushort* proj  = (ushort*)ws;                        // 32000*600*2      = 38,400,000
    ushort* h     = (ushort*)(ws + 38400000);           // 384*256*160*2    = 31,457,280
    float*  c     = (float*)(ws + 69857280);            // 384*256*160*4    = 62,914,560
    short*  Wt    = (short*)(ws + 132771840);           // 608*320*2        = 389,120
    short*  Uti   = (short*)(ws + 133160960);           // 464*160*2        = 148,480
    short*  Utf   = (short*)(ws + 133309440);           // 160*160*2        = 51,200
    float*  biasw = (float*)(ws + 133360640);           // 608*4            = 2,432

    k_prep<<<1153, 256, 0, stream>>>(W_iou, W_f, U_iou, U_f, b_iou, b_f, Wt, Uti, Utf, biasw);
    k_vproj<<<500, 256, 0, stream>>>(emb, Wt, biasw, proj);
    k_leaf<<<46080, 256, 0, stream>>>(tq, tp, tn, proj, h, c);
    k_level<<<43 * 24, 256, 0, stream>>>(21, tq, tp, tn, children, proj, Uti, Utf, h, c);
    k_level<<<16 * 24, 256, 0, stream>>>(5,  tq, tp, tn, children, proj, Uti, Utf, h, c);
    k_level<<<4 * 24, 256, 0, stream>>>(1,   tq, tp, tn, children, proj, Uti, Utf, h, c);
    k_level<<<1 * 24, 256, 0, stream>>>(0,   tq, tp, tn, children, proj, Uti, Utf, h, c);
    k_cos<<<Bb, 64, 0, stream>>>(c, out);
}

// Round 3
// 366.643 us; speedup vs baseline: 3.8236x; 1.1301x over previous
//
#include <hip/hip_runtime.h>
#include <hip/hip_bf16.h>

typedef short short8 __attribute__((ext_vector_type(8)));
typedef float floatx4 __attribute__((ext_vector_type(4)));
typedef unsigned short ushort;

#define Bb 128
#define Nn 256
#define Hh 150
#define HK 160        // padded K / col dim for h,c storage
#define Vv 32000
#define NROW 384      // 3 trees * B
#define PROJC 600

__device__ __forceinline__ float sigf(float x) { return 1.0f / (1.0f + __expf(-x)); }
__device__ __forceinline__ float tanhf_(float x) { return 1.0f - 2.0f / (__expf(2.0f * x) + 1.0f); }
__device__ __forceinline__ float bf2f(ushort s) { union { float f; unsigned u; } v; v.u = ((unsigned)s) << 16; return v.f; }
__device__ __forceinline__ ushort f2bf(float f) { __hip_bfloat16 h = __float2bfloat16(f); return *(ushort*)&h; }

// ---------------- prep: transpose weights to bf16 B-operand layout ----------
// Wt[608][320]  (vocab proj B: cols 0..449 = W_iou, 450..599 = W_f)
// Uti[464][160] (U_iou^T), Utf[160][160] (U_f^T), biasw[608]
__global__ __launch_bounds__(256) void k_prep(
    const float* __restrict__ W_iou, const float* __restrict__ W_f,
    const float* __restrict__ U_iou, const float* __restrict__ U_f,
    const float* __restrict__ b_iou, const float* __restrict__ b_f,
    short* __restrict__ Wt, short* __restrict__ Uti, short* __restrict__ Utf,
    float* __restrict__ biasw)
{
    int idx = blockIdx.x * 256 + threadIdx.x;
    const int nWt = 608 * 320, nUi = 464 * 160, nUf = 160 * 160;
    if (idx < nWt) {
        int n = idx / 320, k = idx % 320;
        float v = 0.f;
        if (k < 300) { if (n < 450) v = W_iou[k * 450 + n]; else if (n < 600) v = W_f[k * 150 + (n - 450)]; }
        Wt[idx] = (short)f2bf(v);
    } else if (idx < nWt + nUi) {
        int i2 = idx - nWt; int n = i2 / 160, k = i2 % 160;
        float v = (k < 150 && n < 450) ? U_iou[k * 450 + n] : 0.f;
        Uti[i2] = (short)f2bf(v);
    } else if (idx < nWt + nUi + nUf) {
        int i2 = idx - nWt - nUi; int n = i2 / 160, k = i2 % 160;
        float v = (k < 150) ? U_f[k * 150 + n] : 0.f;
        Utf[i2] = (short)f2bf(v);
    } else if (idx < nWt + nUi + nUf + 608) {
        int n = idx - nWt - nUi - nUf;
        biasw[n] = n < 450 ? b_iou[n] : (n < 600 ? b_f[n - 450] : 0.f);
    }
}

// ---------------- vocab projection via MFMA: proj[32000][600] bf16 ----------
// block = 32 rows; waves SPLIT the 38 column tiles (no duplicate B loads);
// per tile each wave runs 2 independent MFMA chains (rows 0-15 / 16-31).
__global__ __launch_bounds__(256) void k_vproj(
    const float* __restrict__ emb, const short* __restrict__ Wt,
    const float* __restrict__ biasw, ushort* __restrict__ proj)
{
    __shared__ __align__(16) short As[32 * 328];   // 32 rows x 320 k, stride 328
    const int tid = threadIdx.x;
    const int v0 = blockIdx.x * 32;

    for (int i = tid; i < 32 * 80; i += 256) {
        int r = i / 80, q = i % 80, k0 = q * 4;
        short4 sv;
        if (k0 < 300) {
            float4 x = *(const float4*)(emb + (long)(v0 + r) * 300 + k0);
            sv.x = (short)f2bf(x.x); sv.y = (short)f2bf(x.y);
            sv.z = (short)f2bf(x.z); sv.w = (short)f2bf(x.w);
        } else sv = make_short4(0, 0, 0, 0);
        *(short4*)&As[r * 328 + k0] = sv;
    }
    __syncthreads();

    const int w = tid >> 6, lane = tid & 63;
    const int m = lane & 15, kq = (lane >> 4) * 8;
    const short* a0p = &As[m * 328 + kq];
    const short* a1p = &As[(16 + m) * 328 + kq];

    for (int nt = w; nt < 38; nt += 4) {
        int col = nt * 16 + m;
        const short* bp = Wt + (long)col * 320 + kq;
        floatx4 acc0 = {0.f, 0.f, 0.f, 0.f}, acc1 = {0.f, 0.f, 0.f, 0.f};
        #pragma unroll
        for (int ks = 0; ks < 10; ks++) {
            short8 b  = *(const short8*)(bp + ks * 32);
            short8 a0 = *(const short8*)(a0p + ks * 32);
            short8 a1 = *(const short8*)(a1p + ks * 32);
            acc0 = __builtin_amdgcn_mfma_f32_16x16x32_bf16(a0, b, acc0, 0, 0, 0);
            acc1 = __builtin_amdgcn_mfma_f32_16x16x32_bf16(a1, b, acc1, 0, 0, 0);
        }
        if (col < PROJC) {
            float bias = biasw[col];
            int rb = (lane >> 4) * 4;
            #pragma unroll
            for (int reg = 0; reg < 4; reg++) {
                proj[(long)(v0 + rb + reg) * PROJC + col]      = f2bf(acc0[reg] + bias);
                proj[(long)(v0 + 16 + rb + reg) * PROJC + col] = f2bf(acc1[reg] + bias);
            }
        }
    }
}

// ---------------- leaves: nodes t in [64,256) ----------------
__global__ __launch_bounds__(256) void k_leaf(
    const int* __restrict__ tq, const int* __restrict__ tp, const int* __restrict__ tn,
    const ushort* __restrict__ proj, ushort* __restrict__ h, float* __restrict__ c)
{
    long i = (long)blockIdx.x * 256 + threadIdx.x;   // < 384*192*160 exactly
    int k = (int)(i % HK);
    long rt = i / HK;
    int t = 64 + (int)(rt % 192);
    int rg = (int)(rt / 192);
    long o = ((long)rg * Nn + t) * HK + k;
    if (k >= Hh) { h[o] = 0; c[o] = 0.f; return; }
    int g = rg >> 7, b = rg & 127;
    const int* tok = (g == 0) ? tq : (g == 1 ? tp : tn);
    int v = tok[b * Nn + t];
    const ushort* pr = proj + (long)v * PROJC;
    float iv = sigf(bf2f(pr[k]));
    float ov = sigf(bf2f(pr[150 + k]));
    float uv = tanhf_(bf2f(pr[300 + k]));
    float cv = iv * uv;
    c[o] = cv;
    h[o] = f2bf(ov * tanhf_(cv));
}

// ---------------- internal level: fused MFMA + gates ----------------
// block = (node, 16 rows); 4 waves split the 10 column-tiles; all 7 gate
// segments for one column-tile live in one wave's registers -> no preact LDS.
__global__ __launch_bounds__(256) void k_level(
    int t0,
    const int* __restrict__ tq, const int* __restrict__ tp, const int* __restrict__ tn,
    const int* __restrict__ children, const ushort* __restrict__ proj,
    const short* __restrict__ Uti, const short* __restrict__ Utf,
    ushort* __restrict__ h, float* __restrict__ c)
{
    __shared__ __align__(16) short As[5][16][168];  // seg0=sum, 1..4=children
    __shared__ int ch_s[4];
    __shared__ int tok_s[16];

    const int tid = threadIdx.x;
    const int t = t0 + blockIdx.x / 24;
    const int r0 = (blockIdx.x % 24) * 16;

    if (tid < 4) ch_s[tid] = children[t * 4 + tid];
    if (tid < 16) {
        int rg = r0 + tid, g = rg >> 7, b = rg & 127;
        const int* tok = (g == 0) ? tq : (g == 1 ? tp : tn);
        tok_s[tid] = tok[b * Nn + t];
    }
    __syncthreads();
    const int ch0 = ch_s[0], ch1 = ch_s[1], ch2 = ch_s[2], ch3 = ch_s[3];

    // stage child h rows (bf16) + compute bf16 row-sum
    for (int i = tid; i < 16 * 20; i += 256) {
        int r = i / 20, k0 = (i % 20) * 8;
        long rowb = (long)(r0 + r) * Nn;
        int4 z = make_int4(0, 0, 0, 0);
        int4 v0 = ch0 >= 0 ? *(const int4*)(h + (rowb + ch0) * HK + k0) : z;
        int4 v1 = ch1 >= 0 ? *(const int4*)(h + (rowb + ch1) * HK + k0) : z;
        int4 v2 = ch2 >= 0 ? *(const int4*)(h + (rowb + ch2) * HK + k0) : z;
        int4 v3 = ch3 >= 0 ? *(const int4*)(h + (rowb + ch3) * HK + k0) : z;
        *(int4*)&As[1][r][k0] = v0;
        *(int4*)&As[2][r][k0] = v1;
        *(int4*)&As[3][r][k0] = v2;
        *(int4*)&As[4][r][k0] = v3;
        ushort s[8];
        const ushort* p0 = (const ushort*)&v0; const ushort* p1 = (const ushort*)&v1;
        const ushort* p2 = (const ushort*)&v2; const ushort* p3 = (const ushort*)&v3;
        #pragma unroll
        for (int e = 0; e < 8; e++)
            s[e] = f2bf(bf2f(p0[e]) + bf2f(p1[e]) + bf2f(p2[e]) + bf2f(p3[e]));
        *(int4*)&As[0][r][k0] = *(int4*)s;
    }
    __syncthreads();

    const int w = tid >> 6, lane = tid & 63;
    const int m = lane & 15, kq = (lane >> 4) * 8;

    for (int nt = w; nt < 10; nt += 4) {
        int col = nt * 16 + m;
        const short* bi = Uti + (long)(col) * HK + kq;
        const short* bo = Uti + (long)(150 + col) * HK + kq;
        const short* bu = Uti + (long)(300 + col) * HK + kq;
        const short* bff = Utf + (long)col * HK + kq;
        floatx4 ai = {0.f,0.f,0.f,0.f}, ao = ai, au = ai;
        floatx4 af0 = ai, af1 = ai, af2 = ai, af3 = ai;
        #pragma unroll
        for (int ks = 0; ks < 5; ks++) {
            short8 asum = *(const short8*)&As[0][m][kq + ks * 32];
            short8 ac0  = *(const short8*)&As[1][m][kq + ks * 32];
            short8 ac1  = *(const short8*)&As[2][m][kq + ks * 32];
            short8 ac2  = *(const short8*)&As[3][m][kq + ks * 32];
            short8 ac3  = *(const short8*)&As[4][m][kq + ks * 32];
            short8 vbi = *(const short8*)(bi + ks * 32);
            short8 vbo = *(const short8*)(bo + ks * 32);
            short8 vbu = *(const short8*)(bu + ks * 32);
            short8 vbf = *(const short8*)(bff + ks * 32);
            ai  = __builtin_amdgcn_mfma_f32_16x16x32_bf16(asum, vbi, ai, 0, 0, 0);
            ao  = __builtin_amdgcn_mfma_f32_16x16x32_bf16(asum, vbo, ao, 0, 0, 0);
            au  = __builtin_amdgcn_mfma_f32_16x16x32_bf16(asum, vbu, au, 0, 0, 0);
            af0 = __builtin_amdgcn_mfma_f32_16x16x32_bf16(ac0,  vbf, af0, 0, 0, 0);
            af1 = __builtin_amdgcn_mfma_f32_16x16x32_bf16(ac1,  vbf, af1, 0, 0, 0);
            af2 = __builtin_amdgcn_mfma_f32_16x16x32_bf16(ac2,  vbf, af2, 0, 0, 0);
            af3 = __builtin_amdgcn_mfma_f32_16x16x32_bf16(ac3,  vbf, af3, 0, 0, 0);
        }

        int rbase = (lane >> 4) * 4;
        if (col < Hh) {
            #pragma unroll
            for (int reg = 0; reg < 4; reg++) {
                int r = rbase + reg, rg = r0 + r;
                int v = tok_s[r];
                const ushort* pr = proj + (long)v * PROJC;
                float iv = sigf(bf2f(pr[col])       + ai[reg]);
                float ov = sigf(bf2f(pr[150 + col]) + ao[reg]);
                float uv = tanhf_(bf2f(pr[300 + col]) + au[reg]);
                float fpre = bf2f(pr[450 + col]);
                float cv = iv * uv;
                long crow = (long)rg * Nn;
                if (ch0 >= 0) cv = fmaf(sigf(fpre + af0[reg]), c[(crow + ch0) * HK + col], cv);
                if (ch1 >= 0) cv = fmaf(sigf(fpre + af1[reg]), c[(crow + ch1) * HK + col], cv);
                if (ch2 >= 0) cv = fmaf(sigf(fpre + af2[reg]), c[(crow + ch2) * HK + col], cv);
                if (ch3 >= 0) cv = fmaf(sigf(fpre + af3[reg]), c[(crow + ch3) * HK + col], cv);
                long o = (crow + t) * HK + col;
                c[o] = cv;
                h[o] = f2bf(ov * tanhf_(cv));
            }
        } else {
            #pragma unroll
            for (int reg = 0; reg < 4; reg++) {
                long o = ((long)(r0 + rbase + reg) * Nn + t) * HK + col;
                c[o] = 0.f; h[o] = 0;
            }
        }
    }
}

// ---------------- cosine + triplet loss ----------------
__global__ __launch_bounds__(64) void k_cos(const float* __restrict__ c, float* __restrict__ out)
{
    int b = blockIdx.x, tid = threadIdx.x;
    const float* qc = c + (long)(0 * Bb + b) * Nn * HK;
    const float* pc = c + (long)(1 * Bb + b) * Nn * HK;
    const float* nc = c + (long)(2 * Bb + b) * Nn * HK;
    float qp = 0, qn = 0, qq = 0, pp = 0, nn2 = 0;
    for (int k = tid; k < Hh; k += 64) {
        float qv = qc[k], pv = pc[k], nv = nc[k];
        qp += qv * pv; qn += qv * nv; qq += qv * qv; pp += pv * pv; nn2 += nv * nv;
    }
    #pragma unroll
    for (int off = 32; off > 0; off >>= 1) {
        qp += __shfl_down(qp, off, 64);
        qn += __shfl_down(qn, off, 64);
        qq += __shfl_down(qq, off, 64);
        pp += __shfl_down(pp, off, 64);
        nn2 += __shfl_down(nn2, off, 64);
    }
    if (tid == 0) {
        float a = qp / (sqrtf(qq * pp) + 1e-8f);
        float d = qn / (sqrtf(qq * nn2) + 1e-8f);
        out[b] = fmaxf(0.0f, 1.0f - a + d);
    }
}

extern "C" void kernel_launch(void* const* d_in, const int* in_sizes, int n_in,
                              void* d_out, int out_size, void* d_ws, size_t ws_size,
                              hipStream_t stream)
{
    const int*   tq       = (const int*)d_in[0];
    const int*   tp       = (const int*)d_in[1];
    const int*   tn       = (const int*)d_in[2];
    const int*   children = (const int*)d_in[3];
    const float* emb      = (const float*)d_in[4];
    const float* W_iou    = (const float*)d_in[5];
    const float* U_iou    = (const float*)d_in[6];
    const float* b_iou    = (const float*)d_in[7];
    const float* W_f      = (const float*)d_in[8];
    const float* U_f      = (const float*)d_in[9];
    const float* b_f      = (const float*)d_in[10];
    float* out = (float*)d_out;

    char* ws = (char*)d_ws;
    ushort* proj  = (ushort*)ws;                        // 32000*600*2      = 38,400,000
    ushort* h     = (ushort*)(ws + 38400000);           // 384*256*160*2    = 31,457,280
    float*  c     = (float*)(ws + 69857280);            // 384*256*160*4    = 62,914,560
    short*  Wt    = (short*)(ws + 132771840);           // 608*320*2        = 389,120
    short*  Uti   = (short*)(ws + 133160960);           // 464*160*2        = 148,480
    short*  Utf   = (short*)(ws + 133309440);           // 160*160*2        = 51,200
    float*  biasw = (float*)(ws + 133360640);           // 608*4            = 2,432

    k_prep<<<1153, 256, 0, stream>>>(W_iou, W_f, U_iou, U_f, b_iou, b_f, Wt, Uti, Utf, biasw);
    k_vproj<<<Vv / 32, 256, 0, stream>>>(emb, Wt, biasw, proj);
    k_leaf<<<46080, 256, 0, stream>>>(tq, tp, tn, proj, h, c);
    k_level<<<43 * 24, 256, 0, stream>>>(21, tq, tp, tn, children, proj, Uti, Utf, h, c);
    k_level<<<16 * 24, 256, 0, stream>>>(5,  tq, tp, tn, children, proj, Uti, Utf, h, c);
    k_level<<<4 * 24, 256, 0, stream>>>(1,   tq, tp, tn, children, proj, Uti, Utf, h, c);
    k_level<<<1 * 24, 256, 0, stream>>>(0,   tq, tp, tn, children, proj, Uti, Utf, h, c);
    k_cos<<<Bb, 64, 0, stream>>>(c, out);
}

// Round 4
// 272.806 us; speedup vs baseline: 5.1388x; 1.3440x over previous
//
#include <hip/hip_runtime.h>
#include <hip/hip_bf16.h>

typedef short short8 __attribute__((ext_vector_type(8)));
typedef float floatx4 __attribute__((ext_vector_type(4)));
typedef unsigned short ushort;

#define Bb 128
#define Nn 256
#define Hh 150
#define HK 160        // padded col dim for h,c storage
#define Vv 32000
#define NROW 384      // 3 trees * B
#define PROJC 600
#define NINT 64       // internal nodes per tree (0..63)
#define ZROW (Vv + NROW * NINT)   // 56576: zero sentinel row

__device__ __forceinline__ float sigf(float x) { return 1.0f / (1.0f + __expf(-x)); }
__device__ __forceinline__ float tanhf_(float x) { return 1.0f - 2.0f / (__expf(2.0f * x) + 1.0f); }
__device__ __forceinline__ float bf2f(ushort s) { union { float f; unsigned u; } v; v.u = ((unsigned)s) << 16; return v.f; }
__device__ __forceinline__ ushort f2bf(float f) { __hip_bfloat16 h = __float2bfloat16(f); return *(ushort*)&h; }

// ---------------- prep: weights -> bf16 B-operand layout + zero sentinel ----
__global__ __launch_bounds__(256) void k_prep(
    const float* __restrict__ W_iou, const float* __restrict__ W_f,
    const float* __restrict__ U_iou, const float* __restrict__ U_f,
    const float* __restrict__ b_iou, const float* __restrict__ b_f,
    short* __restrict__ Wt, short* __restrict__ Uti, short* __restrict__ Utf,
    float* __restrict__ biasw, ushort* __restrict__ h_u, float* __restrict__ c_u)
{
    int idx = blockIdx.x * 256 + threadIdx.x;
    const int nWt = 608 * 320, nUi = 464 * 160, nUf = 160 * 160;
    if (idx < nWt) {
        int n = idx / 320, k = idx % 320;
        float v = 0.f;
        if (k < 300) { if (n < 450) v = W_iou[k * 450 + n]; else if (n < 600) v = W_f[k * 150 + (n - 450)]; }
        Wt[idx] = (short)f2bf(v);
    } else if (idx < nWt + nUi) {
        int i2 = idx - nWt; int n = i2 / 160, k = i2 % 160;
        float v = (k < 150 && n < 450) ? U_iou[k * 450 + n] : 0.f;
        Uti[i2] = (short)f2bf(v);
    } else if (idx < nWt + nUi + nUf) {
        int i2 = idx - nWt - nUi; int n = i2 / 160, k = i2 % 160;
        float v = (k < 150) ? U_f[k * 150 + n] : 0.f;
        Utf[i2] = (short)f2bf(v);
    } else if (idx < nWt + nUi + nUf + 608) {
        int n = idx - nWt - nUi - nUf;
        biasw[n] = n < 450 ? b_iou[n] : (n < 600 ? b_f[n - 450] : 0.f);
    } else if (idx < nWt + nUi + nUf + 608 + HK) {
        int k = idx - (nWt + nUi + nUf + 608);
        h_u[(long)ZROW * HK + k] = 0;
        c_u[(long)ZROW * HK + k] = 0.f;
    }
}

// ---------------- vocab projection via MFMA: proj[32000][600] bf16 ----------
// A fragments held in registers (reused across all 38 col tiles): no per-tile LDS.
__global__ __launch_bounds__(256) void k_vproj(
    const float* __restrict__ emb, const short* __restrict__ Wt,
    const float* __restrict__ biasw, ushort* __restrict__ proj)
{
    __shared__ __align__(16) short As[32 * 328];
    const int tid = threadIdx.x;
    const int v0 = blockIdx.x * 32;

    for (int i = tid; i < 32 * 80; i += 256) {
        int r = i / 80, q = i % 80, k0 = q * 4;
        short4 sv;
        if (k0 < 300) {
            float4 x = *(const float4*)(emb + (long)(v0 + r) * 300 + k0);
            sv.x = (short)f2bf(x.x); sv.y = (short)f2bf(x.y);
            sv.z = (short)f2bf(x.z); sv.w = (short)f2bf(x.w);
        } else sv = make_short4(0, 0, 0, 0);
        *(short4*)&As[r * 328 + k0] = sv;
    }
    __syncthreads();

    const int w = tid >> 6, lane = tid & 63;
    const int m = lane & 15, kq = (lane >> 4) * 8;

    short8 a0[10], a1[10];
    #pragma unroll
    for (int ks = 0; ks < 10; ks++) {
        a0[ks] = *(const short8*)&As[m * 328 + kq + ks * 32];
        a1[ks] = *(const short8*)&As[(16 + m) * 328 + kq + ks * 32];
    }

    for (int nt = w; nt < 38; nt += 4) {
        int col = nt * 16 + m;
        const short* bp = Wt + (long)col * 320 + kq;
        floatx4 acc0 = {0.f, 0.f, 0.f, 0.f}, acc1 = {0.f, 0.f, 0.f, 0.f};
        #pragma unroll
        for (int ks = 0; ks < 10; ks++) {
            short8 b = *(const short8*)(bp + ks * 32);
            acc0 = __builtin_amdgcn_mfma_f32_16x16x32_bf16(a0[ks], b, acc0, 0, 0, 0);
            acc1 = __builtin_amdgcn_mfma_f32_16x16x32_bf16(a1[ks], b, acc1, 0, 0, 0);
        }
        if (col < PROJC) {
            float bias = biasw[col];
            int rb = (lane >> 4) * 4;
            #pragma unroll
            for (int reg = 0; reg < 4; reg++) {
                proj[(long)(v0 + rb + reg) * PROJC + col]      = f2bf(acc0[reg] + bias);
                proj[(long)(v0 + 16 + rb + reg) * PROJC + col] = f2bf(acc1[reg] + bias);
            }
        }
    }
}

// ---------------- vocab leaf tables: rows 0..31999 of h_u/c_u ----------------
// leaf gates depend only on token id -> compute once per vocab entry.
__global__ __launch_bounds__(256) void k_vleaf(
    const ushort* __restrict__ proj, ushort* __restrict__ h_u, float* __restrict__ c_u)
{
    int idx = blockIdx.x * 256 + threadIdx.x;      // < 32000*20
    int v = idx / 20, k0 = (idx % 20) * 8;
    const ushort* pr = proj + (long)v * PROJC;
    ushort hv[8]; float cvv[8];
    #pragma unroll
    for (int e = 0; e < 8; e++) {
        int k = k0 + e;
        if (k < Hh) {
            float iv = sigf(bf2f(pr[k]));
            float ov = sigf(bf2f(pr[150 + k]));
            float uv = tanhf_(bf2f(pr[300 + k]));
            float cc = iv * uv;
            cvv[e] = cc;
            hv[e] = f2bf(ov * tanhf_(cc));
        } else { cvv[e] = 0.f; hv[e] = 0; }
    }
    *(int4*)(h_u + (long)v * HK + k0) = *(int4*)hv;
    *(float4*)(c_u + (long)v * HK + k0)     = make_float4(cvv[0], cvv[1], cvv[2], cvv[3]);
    *(float4*)(c_u + (long)v * HK + k0 + 4) = make_float4(cvv[4], cvv[5], cvv[6], cvv[7]);
}

// ---------------- internal level: fused MFMA + gates, unified state ---------
__global__ __launch_bounds__(256) void k_level(
    int t0,
    const int* __restrict__ tq, const int* __restrict__ tp, const int* __restrict__ tn,
    const int* __restrict__ children, const ushort* __restrict__ proj,
    const short* __restrict__ Uti, const short* __restrict__ Utf,
    ushort* __restrict__ h_u, float* __restrict__ c_u)
{
    __shared__ __align__(16) short As[5][16][168];  // seg0=sum, 1..4=children
    __shared__ int idx_s[16][4];
    __shared__ int tok_s[16];

    const int tid = threadIdx.x;
    const int t = t0 + blockIdx.x / 24;
    const int r0 = (blockIdx.x % 24) * 16;

    if (tid < 64) {
        int r = tid >> 2, j = tid & 3;
        int rg = r0 + r, g = rg >> 7, b = rg & 127;
        const int* tok = (g == 0) ? tq : (g == 1 ? tp : tn);
        int ch = children[t * 4 + j];
        int idx;
        if (ch < 0)        idx = ZROW;
        else if (ch >= 64) idx = tok[b * Nn + ch];          // leaf: vocab row
        else               idx = Vv + rg * NINT + ch;       // internal row
        idx_s[r][j] = idx;
        if (j == 0) tok_s[r] = tok[b * Nn + t];
    }
    __syncthreads();

    // stage child h rows (bf16) + bf16 row-sum
    for (int i = tid; i < 16 * 20; i += 256) {
        int r = i / 20, k0 = (i % 20) * 8;
        int4 v0 = *(const int4*)(h_u + (long)idx_s[r][0] * HK + k0);
        int4 v1 = *(const int4*)(h_u + (long)idx_s[r][1] * HK + k0);
        int4 v2 = *(const int4*)(h_u + (long)idx_s[r][2] * HK + k0);
        int4 v3 = *(const int4*)(h_u + (long)idx_s[r][3] * HK + k0);
        *(int4*)&As[1][r][k0] = v0;
        *(int4*)&As[2][r][k0] = v1;
        *(int4*)&As[3][r][k0] = v2;
        *(int4*)&As[4][r][k0] = v3;
        ushort s[8];
        const ushort* p0 = (const ushort*)&v0; const ushort* p1 = (const ushort*)&v1;
        const ushort* p2 = (const ushort*)&v2; const ushort* p3 = (const ushort*)&v3;
        #pragma unroll
        for (int e = 0; e < 8; e++)
            s[e] = f2bf(bf2f(p0[e]) + bf2f(p1[e]) + bf2f(p2[e]) + bf2f(p3[e]));
        *(int4*)&As[0][r][k0] = *(int4*)s;
    }
    __syncthreads();

    const int w = tid >> 6, lane = tid & 63;
    const int m = lane & 15, kq = (lane >> 4) * 8;

    for (int nt = w; nt < 10; nt += 4) {
        int col = nt * 16 + m;
        const short* bi  = Uti + (long)(col) * HK + kq;
        const short* bo  = Uti + (long)(150 + col) * HK + kq;
        const short* bu  = Uti + (long)(300 + col) * HK + kq;
        const short* bff = Utf + (long)col * HK + kq;
        floatx4 ai = {0.f,0.f,0.f,0.f}, ao = ai, au = ai;
        floatx4 af0 = ai, af1 = ai, af2 = ai, af3 = ai;
        #pragma unroll
        for (int ks = 0; ks < 5; ks++) {
            short8 asum = *(const short8*)&As[0][m][kq + ks * 32];
            short8 ac0  = *(const short8*)&As[1][m][kq + ks * 32];
            short8 ac1  = *(const short8*)&As[2][m][kq + ks * 32];
            short8 ac2  = *(const short8*)&As[3][m][kq + ks * 32];
            short8 ac3  = *(const short8*)&As[4][m][kq + ks * 32];
            short8 vbi = *(const short8*)(bi + ks * 32);
            short8 vbo = *(const short8*)(bo + ks * 32);
            short8 vbu = *(const short8*)(bu + ks * 32);
            short8 vbf = *(const short8*)(bff + ks * 32);
            ai  = __builtin_amdgcn_mfma_f32_16x16x32_bf16(asum, vbi, ai, 0, 0, 0);
            ao  = __builtin_amdgcn_mfma_f32_16x16x32_bf16(asum, vbo, ao, 0, 0, 0);
            au  = __builtin_amdgcn_mfma_f32_16x16x32_bf16(asum, vbu, au, 0, 0, 0);
            af0 = __builtin_amdgcn_mfma_f32_16x16x32_bf16(ac0,  vbf, af0, 0, 0, 0);
            af1 = __builtin_amdgcn_mfma_f32_16x16x32_bf16(ac1,  vbf, af1, 0, 0, 0);
            af2 = __builtin_amdgcn_mfma_f32_16x16x32_bf16(ac2,  vbf, af2, 0, 0, 0);
            af3 = __builtin_amdgcn_mfma_f32_16x16x32_bf16(ac3,  vbf, af3, 0, 0, 0);
        }

        int rbase = (lane >> 4) * 4;
        if (col < Hh) {
            #pragma unroll
            for (int reg = 0; reg < 4; reg++) {
                int r = rbase + reg, rg = r0 + r;
                const ushort* pr = proj + (long)tok_s[r] * PROJC;
                float iv = sigf(bf2f(pr[col])        + ai[reg]);
                float ov = sigf(bf2f(pr[150 + col])  + ao[reg]);
                float uv = tanhf_(bf2f(pr[300 + col]) + au[reg]);
                float fpre = bf2f(pr[450 + col]);
                float cv = iv * uv;
                cv = fmaf(sigf(fpre + af0[reg]), c_u[(long)idx_s[r][0] * HK + col], cv);
                cv = fmaf(sigf(fpre + af1[reg]), c_u[(long)idx_s[r][1] * HK + col], cv);
                cv = fmaf(sigf(fpre + af2[reg]), c_u[(long)idx_s[r][2] * HK + col], cv);
                cv = fmaf(sigf(fpre + af3[reg]), c_u[(long)idx_s[r][3] * HK + col], cv);
                long o = (long)(Vv + rg * NINT + t) * HK + col;
                c_u[o] = cv;
                h_u[o] = f2bf(ov * tanhf_(cv));
            }
        } else {
            #pragma unroll
            for (int reg = 0; reg < 4; reg++) {
                long o = (long)(Vv + (r0 + rbase + reg) * NINT + t) * HK + col;
                c_u[o] = 0.f; h_u[o] = 0;
            }
        }
    }
}

// ---------------- cosine + triplet loss ----------------
__global__ __launch_bounds__(64) void k_cos(const float* __restrict__ c_u, float* __restrict__ out)
{
    int b = blockIdx.x, tid = threadIdx.x;
    const float* qc = c_u + (long)(Vv + (0 * Bb + b) * NINT) * HK;
    const float* pc = c_u + (long)(Vv + (1 * Bb + b) * NINT) * HK;
    const float* nc = c_u + (long)(Vv + (2 * Bb + b) * NINT) * HK;
    float qp = 0, qn = 0, qq = 0, pp = 0, nn2 = 0;
    for (int k = tid; k < Hh; k += 64) {
        float qv = qc[k], pv = pc[k], nv = nc[k];
        qp += qv * pv; qn += qv * nv; qq += qv * qv; pp += pv * pv; nn2 += nv * nv;
    }
    #pragma unroll
    for (int off = 32; off > 0; off >>= 1) {
        qp += __shfl_down(qp, off, 64);
        qn += __shfl_down(qn, off, 64);
        qq += __shfl_down(qq, off, 64);
        pp += __shfl_down(pp, off, 64);
        nn2 += __shfl_down(nn2, off, 64);
    }
    if (tid == 0) {
        float a = qp / (sqrtf(qq * pp) + 1e-8f);
        float d = qn / (sqrtf(qq * nn2) + 1e-8f);
        out[b] = fmaxf(0.0f, 1.0f - a + d);
    }
}

extern "C" void kernel_launch(void* const* d_in, const int* in_sizes, int n_in,
                              void* d_out, int out_size, void* d_ws, size_t ws_size,
                              hipStream_t stream)
{
    const int*   tq       = (const int*)d_in[0];
    const int*   tp       = (const int*)d_in[1];
    const int*   tn       = (const int*)d_in[2];
    const int*   children = (const int*)d_in[3];
    const float* emb      = (const float*)d_in[4];
    const float* W_iou    = (const float*)d_in[5];
    const float* U_iou    = (const float*)d_in[6];
    const float* b_iou    = (const float*)d_in[7];
    const float* W_f      = (const float*)d_in[8];
    const float* U_f      = (const float*)d_in[9];
    const float* b_f      = (const float*)d_in[10];
    float* out = (float*)d_out;

    char* ws = (char*)d_ws;
    ushort* proj  = (ushort*)ws;                        // 32000*600*2          = 38,400,000
    ushort* h_u   = (ushort*)(ws + 38400000);           // 56577*160*2          = 18,104,640
    float*  c_u   = (float*)(ws + 56504640);            // 56577*160*4          = 36,209,280
    short*  Wt    = (short*)(ws + 92713920);            // 608*320*2            = 389,120
    short*  Uti   = (short*)(ws + 93103040);            // 464*160*2            = 148,480
    short*  Utf   = (short*)(ws + 93251520);            // 160*160*2            = 51,200
    float*  biasw = (float*)(ws + 93302720);            // 608*4                = 2,432

    k_prep<<<1153, 256, 0, stream>>>(W_iou, W_f, U_iou, U_f, b_iou, b_f,
                                     Wt, Uti, Utf, biasw, h_u, c_u);
    k_vproj<<<Vv / 32, 256, 0, stream>>>(emb, Wt, biasw, proj);
    k_vleaf<<<2500, 256, 0, stream>>>(proj, h_u, c_u);
    k_level<<<43 * 24, 256, 0, stream>>>(21, tq, tp, tn, children, proj, Uti, Utf, h_u, c_u);
    k_level<<<16 * 24, 256, 0, stream>>>(5,  tq, tp, tn, children, proj, Uti, Utf, h_u, c_u);
    k_level<<<4 * 24, 256, 0, stream>>>(1,   tq, tp, tn, children, proj, Uti, Utf, h_u, c_u);
    k_level<<<1 * 24, 256, 0, stream>>>(0,   tq, tp, tn, children, proj, Uti, Utf, h_u, c_u);
    k_cos<<<Bb, 64, 0, stream>>>(c_u, out);
}